// Round 1
// baseline (757.728 us; speedup 1.0000x reference)
//
#include <hip/hip_runtime.h>
#include <hip/hip_bf16.h>

#define N_B 1024
#define N_ITEMS 100000
#define N_CLUSTERS 10
#define N_D 64

// ---------------------------------------------------------------------------
// Kernel 1: S1[c][d] = sum_{i: cluster[i]==c} W1[i][d]   (10 x 64)
//           counts[c] = |{i: cluster[i]==c}|
// Per-wave exclusive LDS accumulation (lane owns column d=lane), block-level
// reduce, then one global atomicAdd per (c,d) per block.
// ---------------------------------------------------------------------------
__global__ __launch_bounds__(256) void k1_segsum(
    const int* __restrict__ cl, const float* __restrict__ W1,
    float* __restrict__ S1g, float* __restrict__ cntg) {
  __shared__ float s1[4][N_CLUSTERS][N_D];   // 10240 B
  __shared__ float cnt[4][N_CLUSTERS];
  int t = threadIdx.x;
  int wave = t >> 6, lane = t & 63;
  float* fs1 = (float*)s1;
  for (int i = t; i < 4 * N_CLUSTERS * N_D; i += 256) fs1[i] = 0.f;
  if (t < 4 * N_CLUSTERS) ((float*)cnt)[t] = 0.f;
  __syncthreads();

  int gw = blockIdx.x * 4 + wave;
  int nw = gridDim.x * 4;
  for (int i = gw; i < N_ITEMS; i += nw) {
    int c = cl[i];                              // wave-uniform
    float w = W1[(size_t)i * N_D + lane];       // coalesced 256B/row
    s1[wave][c][lane] += w;                     // lane-exclusive, no race
    if (lane == 0) cnt[wave][c] += 1.f;
  }
  __syncthreads();

  for (int i = t; i < N_CLUSTERS * N_D; i += 256) {
    float v = fs1[i] + fs1[640 + i] + fs1[1280 + i] + fs1[1920 + i];
    atomicAdd(&S1g[i], v);
  }
  if (t < N_CLUSTERS) {
    float v = cnt[0][t] + cnt[1][t] + cnt[2][t] + cnt[3][t];
    atomicAdd(&cntg[t], v);
  }
}

// ---------------------------------------------------------------------------
// Kernel 2: h = input_array @ S1   (1024 x 64), one thread per element.
// Within a wave: row uniform -> input loads scalar; d = lane -> S1 coalesced.
// ---------------------------------------------------------------------------
__global__ __launch_bounds__(256) void k2_h(
    const float* __restrict__ inp, const float* __restrict__ S1g,
    float* __restrict__ h) {
  int idx = blockIdx.x * 256 + threadIdx.x;    // < 65536 exactly
  int row = idx >> 6, d = idx & 63;
  float acc = 0.f;
#pragma unroll
  for (int c = 0; c < N_CLUSTERS; ++c)
    acc += inp[row * N_CLUSTERS + c] * S1g[c * N_D + d];
  h[idx] = acc;
}

// ---------------------------------------------------------------------------
// Kernel 3 (hot): for each (row, item): logit = h[row,:] . W2[:,item];
// accumulate exp(logit) into per-(row,cluster) buckets. No max-subtraction
// needed (|logit| < ~5, fp32 safe; softmax is shift-invariant).
// Block: 256 threads x 4 items (float4) x ROWS rows. blockIdx.x = row tile
// (fast dim -> consecutive blocks share the same W2 chunk for L2 locality),
// blockIdx.y = item chunk.
// ---------------------------------------------------------------------------
#define ROWS 16
#define CHUNK 1024
__global__ __launch_bounds__(256) void k3_main(
    const float* __restrict__ W2, const float* __restrict__ hmat,
    const int* __restrict__ cl, float* __restrict__ bucketg) {
  __shared__ float bkt[ROWS][N_CLUSTERS];
  int t = threadIdx.x;
  int r0 = blockIdx.x * ROWS;                  // 0..1023
  int j0 = blockIdx.y * CHUNK + t * 4;         // item base for this thread

  if (t < ROWS * N_CLUSTERS) ((float*)bkt)[t] = 0.f;
  __syncthreads();

  bool active = (j0 < N_ITEMS);                // N_ITEMS % 4 == 0: all-or-none
  if (active) {
    const float* __restrict__ hb = hmat + (size_t)r0 * N_D;
    float4 acc[ROWS];
#pragma unroll
    for (int r = 0; r < ROWS; ++r) acc[r] = make_float4(0.f, 0.f, 0.f, 0.f);

#pragma unroll 4
    for (int d = 0; d < N_D; ++d) {
      float4 w = *(const float4*)(W2 + (size_t)d * N_ITEMS + j0);  // coalesced
#pragma unroll
      for (int r = 0; r < ROWS; ++r) {
        float hs = hb[r * N_D + d];            // wave-uniform -> s_load
        acc[r].x += hs * w.x;
        acc[r].y += hs * w.y;
        acc[r].z += hs * w.z;
        acc[r].w += hs * w.w;
      }
    }

    int4 c4 = *(const int4*)(cl + j0);
#pragma unroll
    for (int r = 0; r < ROWS; ++r) {
      atomicAdd(&bkt[r][c4.x], __expf(acc[r].x));
      atomicAdd(&bkt[r][c4.y], __expf(acc[r].y));
      atomicAdd(&bkt[r][c4.z], __expf(acc[r].z));
      atomicAdd(&bkt[r][c4.w], __expf(acc[r].w));
    }
  }
  __syncthreads();

  if (t < ROWS * N_CLUSTERS) {
    int r = t / N_CLUSTERS, c = t % N_CLUSTERS;
    atomicAdd(&bucketg[(size_t)(r0 + r) * N_CLUSTERS + c], bkt[r][c]);
  }
}

// ---------------------------------------------------------------------------
// Kernel 4: out[b][c] = bucket[b][c] / (sum_c' bucket[b][c']) / max(cnt[c],1)
// ---------------------------------------------------------------------------
__global__ __launch_bounds__(256) void k4_fin(
    const float* __restrict__ bucketg, const float* __restrict__ cntg,
    float* __restrict__ out) {
  int idx = blockIdx.x * 256 + threadIdx.x;
  if (idx >= N_B * N_CLUSTERS) return;
  int row = idx / N_CLUSTERS, c = idx % N_CLUSTERS;
  const float* b = bucketg + (size_t)row * N_CLUSTERS;
  float total = 0.f;
#pragma unroll
  for (int k = 0; k < N_CLUSTERS; ++k) total += b[k];
  out[idx] = b[c] / (total * fmaxf(cntg[c], 1.f));
}

// ---------------------------------------------------------------------------
// Workspace layout (floats):
//   [0,    640)   S1
//   [640,  650)   counts
//   [1024, 11264) buckets (1024 x 10)
//   [12288,77824) h (1024 x 64)
// Zero region: first 11264 floats (S1 + counts + buckets). h fully written.
// Total ws use: ~311 KB.
// ---------------------------------------------------------------------------
extern "C" void kernel_launch(void* const* d_in, const int* in_sizes, int n_in,
                              void* d_out, int out_size, void* d_ws, size_t ws_size,
                              hipStream_t stream) {
  const float* input = (const float*)d_in[0];   // (1024, 10) f32
  const int* cl      = (const int*)d_in[1];     // (100000,) i32
  const float* W1    = (const float*)d_in[2];   // (100000, 64) f32
  const float* W2    = (const float*)d_in[3];   // (64, 100000) f32
  float* out = (float*)d_out;                   // (1024, 10) f32
  float* ws = (float*)d_ws;

  float* S1g     = ws;           // 640
  float* cntg    = ws + 640;     // 10
  float* bucketg = ws + 1024;    // 10240
  float* h       = ws + 12288;   // 65536

  hipMemsetAsync(d_ws, 0, (size_t)11264 * sizeof(float), stream);

  k1_segsum<<<256, 256, 0, stream>>>(cl, W1, S1g, cntg);
  k2_h<<<256, 256, 0, stream>>>(input, S1g, h);

  dim3 g3(N_B / ROWS, (N_ITEMS + CHUNK - 1) / CHUNK);  // (64, 98)
  k3_main<<<g3, 256, 0, stream>>>(W2, h, cl, bucketg);

  k4_fin<<<(N_B * N_CLUSTERS + 255) / 256, 256, 0, stream>>>(bucketg, cntg, out);
}

// Round 2
// 709.490 us; speedup vs baseline: 1.0680x; 1.0680x over previous
//
#include <hip/hip_runtime.h>
#include <hip/hip_bf16.h>

#define N_B 1024
#define N_ITEMS 100000
#define N_CLUSTERS 10
#define N_D 64

// ---------------------------------------------------------------------------
// Kernel 1: S1[c][d] = sum_{i: cluster[i]==c} W1[i][d]; counts[c].
// Register accumulators per cluster (predicated selects) -> no LDS RMW chain.
// lane = d column; item index wave-uniform -> cl via s_load, W1 coalesced.
// ---------------------------------------------------------------------------
__global__ __launch_bounds__(256) void k1_segsum(
    const int* __restrict__ cl, const float* __restrict__ W1,
    float* __restrict__ S1g, float* __restrict__ cntg) {
  __shared__ float s1[4][N_CLUSTERS][N_D];   // 10 KB
  __shared__ float scnt[4][N_CLUSTERS];
  int t = threadIdx.x;
  int wave = t >> 6, lane = t & 63;

  float a[N_CLUSTERS];
  float cn[N_CLUSTERS];
#pragma unroll
  for (int k = 0; k < N_CLUSTERS; ++k) { a[k] = 0.f; cn[k] = 0.f; }

  int gw = blockIdx.x * 4 + wave;
  int nw = gridDim.x * 4;
#pragma unroll 4
  for (int i = gw; i < N_ITEMS; i += nw) {
    int c = cl[i];                              // wave-uniform -> s_load
    float w = W1[(size_t)i * N_D + lane];       // coalesced 256B/row
#pragma unroll
    for (int k = 0; k < N_CLUSTERS; ++k) {
      bool m = (c == k);
      a[k] += m ? w : 0.f;
      cn[k] += m ? 1.f : 0.f;
    }
  }

#pragma unroll
  for (int k = 0; k < N_CLUSTERS; ++k) s1[wave][k][lane] = a[k];
  if (lane == 0) {
#pragma unroll
    for (int k = 0; k < N_CLUSTERS; ++k) scnt[wave][k] = cn[k];
  }
  __syncthreads();

  const float* fs1 = (const float*)s1;
  for (int i = t; i < N_CLUSTERS * N_D; i += 256) {
    float v = fs1[i] + fs1[640 + i] + fs1[1280 + i] + fs1[1920 + i];
    atomicAdd(&S1g[i], v);
  }
  if (t < N_CLUSTERS) {
    float v = scnt[0][t] + scnt[1][t] + scnt[2][t] + scnt[3][t];
    atomicAdd(&cntg[t], v);
  }
}

// ---------------------------------------------------------------------------
// Kernel 2: hT[d][row] = sum_c input[row][c] * S1[c][d]   (64 x 1024,
// TRANSPOSED so k3 can s_load 64 contiguous row-values per d).
// ---------------------------------------------------------------------------
__global__ __launch_bounds__(256) void k2_h(
    const float* __restrict__ inp, const float* __restrict__ S1g,
    float* __restrict__ hT) {
  int idx = blockIdx.x * 256 + threadIdx.x;    // < 65536 exactly
  int d = idx >> 10, row = idx & 1023;         // wave: d uniform, rows stride-1
  float acc = 0.f;
#pragma unroll
  for (int c = 0; c < N_CLUSTERS; ++c)
    acc += inp[row * N_CLUSTERS + c] * S1g[c * N_D + d];  // S1 wave-uniform
  hT[idx] = acc;                               // coalesced
}

// ---------------------------------------------------------------------------
// Kernel 3 (hot): block = 64 rows x 256 items. Thread owns 1 item, acc[64]
// rows in VGPRs. W2 column preloaded in 16-d chunks (independent coalesced
// loads, software-prefetched) -> high MLP, no VMEM in the FMA loop.
// h broadcast per d comes from contiguous uniform loads (s_load_dwordx16).
// Epilogue: exp -> per-wave x4-replicated LDS buckets -> global atomics.
// ---------------------------------------------------------------------------
#define ROWS 64
#define REP 4
__global__ __launch_bounds__(256) void k3_main(
    const float* __restrict__ W2, const float* __restrict__ hT,
    const int* __restrict__ cl, float* __restrict__ bucketg) {
  __shared__ float bkt[4][ROWS][N_CLUSTERS * REP];   // 40 KB
  int t = threadIdx.x;
  int wave = t >> 6, lane = t & 63;
  int r0 = blockIdx.x * ROWS;                  // 0..960
  int j = blockIdx.y * 256 + t;
  bool valid = (j < N_ITEMS);
  int jc = valid ? j : (N_ITEMS - 1);          // clamp: loads in-bounds

  float* fb = (float*)bkt;
#pragma unroll
  for (int i = 0; i < 4 * ROWS * N_CLUSTERS * REP / 256; ++i)
    fb[t + i * 256] = 0.f;
  __syncthreads();

  float acc[ROWS];
#pragma unroll
  for (int r = 0; r < ROWS; ++r) acc[r] = 0.f;

  const float* __restrict__ w2col = W2 + jc;

  float w[16], wn[16];
#pragma unroll
  for (int k = 0; k < 16; ++k)                 // chunk 0: 16 independent loads
    w[k] = w2col[(size_t)k * N_ITEMS];

  for (int d0 = 0; d0 < N_D; d0 += 16) {
    if (d0 + 16 < N_D) {
#pragma unroll
      for (int k = 0; k < 16; ++k)             // prefetch next chunk
        wn[k] = w2col[(size_t)(d0 + 16 + k) * N_ITEMS];
    }
#pragma unroll
    for (int k = 0; k < 16; ++k) {
      const float* hrow = hT + (size_t)(d0 + k) * N_B + r0;  // uniform addr
      float hv[ROWS];
#pragma unroll
      for (int r = 0; r < ROWS; ++r) hv[r] = hrow[r];        // s_load x16
#pragma unroll
      for (int r = 0; r < ROWS; ++r)
        acc[r] = fmaf(hv[r], w[k], acc[r]);    // SGPR-broadcast FMA
    }
#pragma unroll
    for (int k = 0; k < 16; ++k) w[k] = wn[k];
  }

  if (valid) {
    int c = cl[j];
    int slot = c * REP + (lane & (REP - 1));
#pragma unroll
    for (int r = 0; r < ROWS; ++r)
      atomicAdd(&bkt[wave][r][slot], __expf(acc[r]));
  }
  __syncthreads();

  for (int i = t; i < ROWS * N_CLUSTERS; i += 256) {
    int r = i / N_CLUSTERS, c = i % N_CLUSTERS;
    float v = 0.f;
#pragma unroll
    for (int wv = 0; wv < 4; ++wv)
#pragma unroll
      for (int p = 0; p < REP; ++p) v += bkt[wv][r][c * REP + p];
    atomicAdd(&bucketg[(size_t)(r0 + r) * N_CLUSTERS + c], v);
  }
}

// ---------------------------------------------------------------------------
// Kernel 4: out[b][c] = bucket[b][c] / (sum_c' bucket[b][c']) / max(cnt[c],1)
// ---------------------------------------------------------------------------
__global__ __launch_bounds__(256) void k4_fin(
    const float* __restrict__ bucketg, const float* __restrict__ cntg,
    float* __restrict__ out) {
  int idx = blockIdx.x * 256 + threadIdx.x;
  if (idx >= N_B * N_CLUSTERS) return;
  int row = idx / N_CLUSTERS, c = idx % N_CLUSTERS;
  const float* b = bucketg + (size_t)row * N_CLUSTERS;
  float total = 0.f;
#pragma unroll
  for (int k = 0; k < N_CLUSTERS; ++k) total += b[k];
  out[idx] = b[c] / (total * fmaxf(cntg[c], 1.f));
}

// ---------------------------------------------------------------------------
// Workspace layout (floats):
//   [0,    640)   S1
//   [640,  650)   counts
//   [1024, 11264) buckets (1024 x 10)
//   [12288,77824) hT (64 x 1024, transposed)
// Zero region: first 11264 floats.
// ---------------------------------------------------------------------------
extern "C" void kernel_launch(void* const* d_in, const int* in_sizes, int n_in,
                              void* d_out, int out_size, void* d_ws, size_t ws_size,
                              hipStream_t stream) {
  const float* input = (const float*)d_in[0];   // (1024, 10) f32
  const int* cl      = (const int*)d_in[1];     // (100000,) i32
  const float* W1    = (const float*)d_in[2];   // (100000, 64) f32
  const float* W2    = (const float*)d_in[3];   // (64, 100000) f32
  float* out = (float*)d_out;                   // (1024, 10) f32
  float* ws = (float*)d_ws;

  float* S1g     = ws;           // 640
  float* cntg    = ws + 640;     // 10
  float* bucketg = ws + 1024;    // 10240
  float* hT      = ws + 12288;   // 65536 (64 x 1024)

  hipMemsetAsync(d_ws, 0, (size_t)11264 * sizeof(float), stream);

  k1_segsum<<<256, 256, 0, stream>>>(cl, W1, S1g, cntg);
  k2_h<<<256, 256, 0, stream>>>(input, S1g, hT);

  dim3 g3(N_B / ROWS, (N_ITEMS + 255) / 256);  // (16, 391), x fast = same chunk
  k3_main<<<g3, 256, 0, stream>>>(W2, hT, cl, bucketg);

  k4_fin<<<(N_B * N_CLUSTERS + 255) / 256, 256, 0, stream>>>(bucketg, cntg, out);
}